// Round 4
// baseline (414.275 us; speedup 1.0000x reference)
//
#include <hip/hip_runtime.h>
#include <hip/hip_bf16.h>

// AttGNN: GAT + GCN on sparse (~1%) 8192-node graph.
// R4: compaction with per-wave private segments (no LDS atomics) and 8
// preloaded float4 per lane (full MLP; one vmcnt wait instead of 8).
// K3/K4 pack the 4 per-wave segments into LDS, then gather as before.
// Floor: one 256 MB read of `sup` (~41 us) + ~250 us fixed harness reset.

#define N_NODES 8192
#define D_IN    128
#define D_GAT   64
#define SLOTS   256               // 4 wave-segments x 64 slots per row
#define SEG     64                // slots per wave segment (keeps ~20 +- 4.5)
#define K1_BLOCKS (N_NODES / 4)   // 2048 blocks of 4 rows

// ---------------- K12: [blocks 0..2047] h=feat@W_map, s=h@U, t=h@V
//                  [blocks 2048..10239] compact sup row -> segmented (col,val)
__global__ __launch_bounds__(256) void k12_map_compact(
    const float* __restrict__ feat, const float* __restrict__ W_map,
    const float* __restrict__ U, const float* __restrict__ V,
    const float* __restrict__ sup,
    float* __restrict__ h, float* __restrict__ s, float* __restrict__ t,
    int* __restrict__ cnt4, int* __restrict__ col, float* __restrict__ val)
{
    if (blockIdx.x < K1_BLOCKS) {
        // ---- K1: 4 rows per block, wave r handles row blockIdx*4+r ----
        const int r = threadIdx.x >> 6;
        const int d = threadIdx.x & 63;
        const int row = blockIdx.x * 4 + r;
        __shared__ float f[4 * D_IN];
        if (threadIdx.x < 128)
            ((float4*)f)[threadIdx.x] =
                ((const float4*)(feat + (size_t)blockIdx.x * 4 * D_IN))[threadIdx.x];
        __syncthreads();
        const float* fr = f + r * D_IN;
        float acc = 0.f;
#pragma unroll 8
        for (int k = 0; k < D_IN; ++k)
            acc += fr[k] * W_map[k * D_GAT + d];
        h[row * D_GAT + d] = acc;
        float sv = acc * U[d];
        float tv = acc * V[d];
#pragma unroll
        for (int off = 32; off > 0; off >>= 1) {
            sv += __shfl_xor(sv, off);
            tv += __shfl_xor(tv, off);
        }
        if (d == 0) { s[row] = sv; t[row] = tv; }
    } else {
        // ---- K2: per-wave-segment ballot compaction of row j ----
        const int j    = blockIdx.x - K1_BLOCKS;
        const int w    = threadIdx.x >> 6;     // wave id: owns elements
        const int lane = threadIdx.x & 63;     //   [w*2048, (w+1)*2048)
        const float4* row = (const float4*)(sup + (size_t)j * N_NODES);
        int*   colw = col + j * SLOTS + w * SEG;
        float* valw = val + j * SLOTS + w * SEG;

        float4 v[8];                           // 8 outstanding loads, 1 wait
#pragma unroll
        for (int it = 0; it < 8; ++it)
            v[it] = row[w * 512 + it * 64 + lane];

        int cw = 0;                            // wave-uniform (scalar) count
        const unsigned long long ltmask = (lane == 63) ? ~0ull >> 1
                                        : (1ull << lane) - 1ull;
#pragma unroll
        for (int it = 0; it < 8; ++it) {
            const int i0 = (w * 512 + it * 64 + lane) * 4;
            const float vs[4] = {v[it].x, v[it].y, v[it].z, v[it].w};
#pragma unroll
            for (int u = 0; u < 4; ++u) {
                const int i = i0 + u;
                const float vv = vs[u] + ((i == j) ? 1.0f : 0.0f); // sup2=sup+I
                const bool keep = vv > 0.f;
                const unsigned long long mask = __ballot(keep);
                if (keep) {
                    const int pos = cw + __popcll(mask & ltmask);
                    if (pos < SEG) { colw[pos] = i; valw[pos] = vv; }
                }
                cw += __popcll(mask);
            }
        }
        if (lane == 0) cnt4[j * 4 + w] = (cw < SEG) ? cw : SEG;
    }
}

// ---------------- K3: GAT row: softmax(tanh(s_i+t_j+b)) aggregate over h ----
// 4 rows/block (one wave each). Pack the 4 segments into LDS, then gather
// with lane=(pp,c16) float4 split, unroll-4.
__global__ __launch_bounds__(256) void k3_gat(
    const float* __restrict__ h, const float* __restrict__ s,
    const float* __restrict__ t, const float* __restrict__ b,
    const int* __restrict__ cnt4, const int* __restrict__ col,
    float* __restrict__ gat)
{
    const int wid  = threadIdx.x >> 6;
    const int lane = threadIdx.x & 63;
    const int j = blockIdx.x * 4 + wid;
    const int* colj = col + j * SLOTS;
    __shared__ int   cl_s[4][SLOTS];
    __shared__ float w_s[4][SLOTS];
    int*   cl = cl_s[wid];
    float* w  = w_s[wid];
    const float tj = t[j] + b[0];

    // pack segments: segment k (count ck) -> cl[Pk .. Pk+ck)
    int m = 0;
#pragma unroll
    for (int k = 0; k < 4; ++k) {
        const int ck = cnt4[j * 4 + k];        // wave-uniform load
        if (lane < ck) cl[m + lane] = colj[k * SEG + lane];
        m += ck;
    }

    float lmax = -1e30f;
    for (int p = lane; p < m; p += 64) {
        const float e = tanhf(s[cl[p]] + tj);
        w[p] = e;
        lmax = fmaxf(lmax, e);
    }
#pragma unroll
    for (int off = 32; off > 0; off >>= 1)
        lmax = fmaxf(lmax, __shfl_xor(lmax, off));

    float lsum = 0.f;
    for (int p = lane; p < m; p += 64) {       // same p-set as writer
        const float e = __expf(w[p] - lmax);
        w[p] = e;
        lsum += e;
    }
#pragma unroll
    for (int off = 32; off > 0; off >>= 1) lsum += __shfl_xor(lsum, off);
    __syncthreads();                           // w[], cl[] visible across lanes

    const int c16 = (lane & 15) * 4;
    const int pp  = lane >> 4;
    float4 a0 = make_float4(0,0,0,0), a1 = a0, a2 = a0, a3 = a0;
    for (int base = 0; base < m; base += 16) {
        const int p0 = base + pp, p1 = p0 + 4, p2 = p0 + 8, p3 = p0 + 12;
        if (p0 < m) { const float wp = w[p0];
            const float4 hv = *(const float4*)(h + cl[p0] * D_GAT + c16);
            a0.x += wp*hv.x; a0.y += wp*hv.y; a0.z += wp*hv.z; a0.w += wp*hv.w; }
        if (p1 < m) { const float wp = w[p1];
            const float4 hv = *(const float4*)(h + cl[p1] * D_GAT + c16);
            a1.x += wp*hv.x; a1.y += wp*hv.y; a1.z += wp*hv.z; a1.w += wp*hv.w; }
        if (p2 < m) { const float wp = w[p2];
            const float4 hv = *(const float4*)(h + cl[p2] * D_GAT + c16);
            a2.x += wp*hv.x; a2.y += wp*hv.y; a2.z += wp*hv.z; a2.w += wp*hv.w; }
        if (p3 < m) { const float wp = w[p3];
            const float4 hv = *(const float4*)(h + cl[p3] * D_GAT + c16);
            a3.x += wp*hv.x; a3.y += wp*hv.y; a3.z += wp*hv.z; a3.w += wp*hv.w; }
    }
    float4 acc;
    acc.x = (a0.x + a1.x) + (a2.x + a3.x);
    acc.y = (a0.y + a1.y) + (a2.y + a3.y);
    acc.z = (a0.z + a1.z) + (a2.z + a3.z);
    acc.w = (a0.w + a1.w) + (a2.w + a3.w);
#pragma unroll
    for (int off = 16; off <= 32; off <<= 1) {
        acc.x += __shfl_xor(acc.x, off); acc.y += __shfl_xor(acc.y, off);
        acc.z += __shfl_xor(acc.z, off); acc.w += __shfl_xor(acc.w, off);
    }
    if (pp == 0) {
        const float inv = 1.0f / lsum;
        float4 o;
        o.x = tanhf(acc.x * inv); o.y = tanhf(acc.y * inv);
        o.z = tanhf(acc.z * inv); o.w = tanhf(acc.w * inv);
        *(float4*)(gat + j * D_GAT + c16) = o;
    }
}

// ---------------- K4: agg = sup2@gat ; out = normalize(relu(agg@W_gcn)) ----
__global__ __launch_bounds__(256) void k4_gcn(
    const float* __restrict__ gat, const float* __restrict__ W_gcn,
    const int* __restrict__ cnt4, const int* __restrict__ col,
    const float* __restrict__ val, float* __restrict__ out)
{
    const int wid  = threadIdx.x >> 6;
    const int lane = threadIdx.x & 63;
    const int j = blockIdx.x * 4 + wid;
    const int*   colj = col + j * SLOTS;
    const float* valj = val + j * SLOTS;
    __shared__ int   cl_s[4][SLOTS];
    __shared__ float wv_s[4][SLOTS];
    __shared__ float a_s[4][D_GAT];
    int*   cl = cl_s[wid];
    float* wv = wv_s[wid];
    float* a  = a_s[wid];

    int m = 0;
#pragma unroll
    for (int k = 0; k < 4; ++k) {
        const int ck = cnt4[j * 4 + k];
        if (lane < ck) {
            cl[m + lane] = colj[k * SEG + lane];
            wv[m + lane] = valj[k * SEG + lane];
        }
        m += ck;
    }
    __syncthreads();                           // cl/wv visible across lanes

    const int c16 = (lane & 15) * 4;
    const int pp  = lane >> 4;
    float4 a0 = make_float4(0,0,0,0), a1 = a0, a2 = a0, a3 = a0;
    for (int base = 0; base < m; base += 16) {
        const int p0 = base + pp, p1 = p0 + 4, p2 = p0 + 8, p3 = p0 + 12;
        if (p0 < m) { const float wp = wv[p0];
            const float4 gv = *(const float4*)(gat + cl[p0] * D_GAT + c16);
            a0.x += wp*gv.x; a0.y += wp*gv.y; a0.z += wp*gv.z; a0.w += wp*gv.w; }
        if (p1 < m) { const float wp = wv[p1];
            const float4 gv = *(const float4*)(gat + cl[p1] * D_GAT + c16);
            a1.x += wp*gv.x; a1.y += wp*gv.y; a1.z += wp*gv.z; a1.w += wp*gv.w; }
        if (p2 < m) { const float wp = wv[p2];
            const float4 gv = *(const float4*)(gat + cl[p2] * D_GAT + c16);
            a2.x += wp*gv.x; a2.y += wp*gv.y; a2.z += wp*gv.z; a2.w += wp*gv.w; }
        if (p3 < m) { const float wp = wv[p3];
            const float4 gv = *(const float4*)(gat + cl[p3] * D_GAT + c16);
            a3.x += wp*gv.x; a3.y += wp*gv.y; a3.z += wp*gv.z; a3.w += wp*gv.w; }
    }
    float4 acc;
    acc.x = (a0.x + a1.x) + (a2.x + a3.x);
    acc.y = (a0.y + a1.y) + (a2.y + a3.y);
    acc.z = (a0.z + a1.z) + (a2.z + a3.z);
    acc.w = (a0.w + a1.w) + (a2.w + a3.w);
#pragma unroll
    for (int off = 16; off <= 32; off <<= 1) {
        acc.x += __shfl_xor(acc.x, off); acc.y += __shfl_xor(acc.y, off);
        acc.z += __shfl_xor(acc.z, off); acc.w += __shfl_xor(acc.w, off);
    }
    if (pp == 0) *(float4*)(a + c16) = acc;
    __syncthreads();

    float o = 0.f;
#pragma unroll 8
    for (int d = 0; d < D_GAT; ++d)
        o += a[d] * W_gcn[d * D_GAT + lane];   // a broadcast, W_gcn L1-hot
    o = fmaxf(o, 0.f);

    float ss = o * o;
#pragma unroll
    for (int off = 32; off > 0; off >>= 1) ss += __shfl_xor(ss, off);
    const float nrm = sqrtf(ss);
    out[j * D_GAT + lane] = o / fmaxf(nrm, 1e-12f);
}

extern "C" void kernel_launch(void* const* d_in, const int* in_sizes, int n_in,
                              void* d_out, int out_size, void* d_ws, size_t ws_size,
                              hipStream_t stream) {
    const float* feat  = (const float*)d_in[0];  // [N,128]
    const float* sup   = (const float*)d_in[1];  // [N,N]
    const float* W_map = (const float*)d_in[2];  // [128,64]
    const float* b_map = (const float*)d_in[3];  // [1]
    const float* U     = (const float*)d_in[4];  // [64,1]
    const float* V     = (const float*)d_in[5];  // [64,1]
    const float* W_gcn = (const float*)d_in[6];  // [64,64]
    float* out = (float*)d_out;

    char* ws = (char*)d_ws;
    float* h    = (float*)(ws);                         // 2 MB
    float* gat  = (float*)(ws + (2u << 20));            // 2 MB
    float* s    = (float*)(ws + (4u << 20));            // 32 KB
    float* t    = (float*)(ws + (4u << 20) + 32768);    // 32 KB
    int*   cnt4 = (int*)  (ws + (4u << 20) + 65536);    // 128 KB (N*4 ints)
    int*   col  = (int*)  (ws + (5u << 20));            // 8 MB
    float* val  = (float*)(ws + (13u << 20));           // 8 MB  (~21 MB total)

    k12_map_compact<<<K1_BLOCKS + N_NODES, 256, 0, stream>>>(
        feat, W_map, U, V, sup, h, s, t, cnt4, col, val);
    k3_gat<<<N_NODES / 4, 256, 0, stream>>>(h, s, t, b_map, cnt4, col, gat);
    k4_gcn<<<N_NODES / 4, 256, 0, stream>>>(gat, W_gcn, cnt4, col, val, out);
}